// Round 12
// baseline (143.099 us; speedup 1.0000x reference)
//
#include <hip/hip_runtime.h>
#include <hip/hip_bf16.h>

#define B_ 8
#define N_ 256
#define H_ 128
#define E_ 32
#define XLS_STRIDE 264   // bf16 elems/row: 256 + 8 pad

typedef __bf16 bf16x8 __attribute__((ext_vector_type(8)));
typedef __bf16 bf16x4 __attribute__((ext_vector_type(4)));
typedef float f32x4 __attribute__((ext_vector_type(4)));

// round-to-nearest-even fp32 -> bf16
static __device__ __forceinline__ __bf16 f2bf(float f) {
    union { float f; unsigned int u; } a;
    a.f = f;
    const unsigned int r = a.u + 0x7FFFu + ((a.u >> 16) & 1u);
    union { unsigned short s; __bf16 b; } o;
    o.s = (unsigned short)(r >> 16);
    return o.b;
}

// ws layout (xbT stored bf16 so total = 776 KiB):
//   xbT  : bf16, elem [0, 262144)            = bytes [0, 524288)
//   W1T  : f32,  float-offset [131072, 163840)
//   W2T  : f32,  float-offset [163840, 196608)
//   Webf : bf16, float-offset 196608, 4096 elems (8 KiB)
#define W1T_OFF  131072
#define W2T_OFF  163840
#define WEBF_OFF 196608

// Prep: (a) xbT[b,h,j] = bf16(x[b,j,h] + be[h]), (b) W1T/W2T transposes,
// (c) We packed as per-lane bf16 MFMA B-fragments (one dwordx4 per tile).
__global__ __launch_bounds__(256) void prep_kernel(
    const float* __restrict__ x, const float* __restrict__ be,
    const float* __restrict__ W1, const float* __restrict__ W2,
    const float* __restrict__ We, float* __restrict__ ws)
{
    const int blk = blockIdx.x;
    if (blk == 320) {               // (c) We fragments: [quad][h][kk] bf16
        __bf16* Webf = (__bf16*)(ws + WEBF_OFF);
        for (int q = threadIdx.x; q < 512; q += 256) {
            const int quad = q >> 7, h = q & 127;
            bf16x8 t;
#pragma unroll
            for (int kk = 0; kk < 8; ++kk)
                t[kk] = f2bf(We[(quad * 8 + kk) * H_ + h]);
            *(bf16x8*)&Webf[q * 8] = t;
        }
        return;
    }
    __shared__ float tile[32][33];
    const int tx = threadIdx.x & 31, ty = threadIdx.x >> 5;   // ty 0..7
    if (blk < 256) {                // (a) per-batch x transpose, bf16 out
        const int b = blk >> 5, t = blk & 31;
        const float* src = x + (size_t)b * N_ * H_;
        __bf16* dst = (__bf16*)ws + (size_t)b * H_ * N_;
        const int r0 = (t >> 2) * 32, c0 = (t & 3) * 32;      // j0, h0
#pragma unroll
        for (int p = 0; p < 4; ++p)
            tile[ty + p * 8][tx] =
                src[(size_t)(r0 + ty + p * 8) * H_ + c0 + tx] + be[c0 + tx];
        __syncthreads();
#pragma unroll
        for (int p = 0; p < 4; ++p)
            dst[(size_t)(c0 + ty + p * 8) * N_ + r0 + tx] = f2bf(tile[tx][ty + p * 8]);
        return;
    }
    // (b) weight transposes (float dst)
    const float* src; float* dst; int R, C, r0, c0;
    if (blk < 288) {                // W1: 128x256 -> 256x128
        const int t = blk - 256;
        src = W1; dst = ws + W1T_OFF;
        R = 128; C = 256; r0 = (t >> 3) * 32; c0 = (t & 7) * 32;
    } else {                        // W2: 256x128 -> 128x256
        const int t = blk - 288;
        src = W2; dst = ws + W2T_OFF;
        R = 256; C = 128; r0 = (t >> 2) * 32; c0 = (t & 3) * 32;
    }
#pragma unroll
    for (int p = 0; p < 4; ++p)
        tile[ty + p * 8][tx] = src[(size_t)(r0 + ty + p * 8) * C + c0 + tx];
    __syncthreads();
#pragma unroll
    for (int p = 0; p < 4; ++p)
        dst[(size_t)(c0 + ty + p * 8) * R + r0 + tx] = tile[tx][ty + p * 8];
}

// Aggregation, r12: h-SPLIT — 2 WGs per (b,i), each owning 64 of the 128 h
// (4 MFMA tiles/wave instead of 8).  Rationale: r8-r11 pinned the kernel at
// 2 waves/SIMD (128-arch-reg wall; the 8-tile structure lives at ~108 regs;
// every attempt to raise occupancy at 8 tiles spilled 130-280 MB).  Halving
// the tile count halves the live set (bw[4]+acc[4]+psum[4]+xv[4] ~ 75 regs)
// so (256,3) fits -> 3 waves/SIMD (+50% latency hiding) and ~35 KB LDS ->
// 3 blocks/CU.  Cost: e/adj read 2x — acceptable, e is L3-resident (67 MB
// < 256 MB L3; measured FETCH 36 MB < e size).
//   h[b,i,hh*64+..] = x[..] + sum_j adj*relu(xb[b,j,..] + e[b,i,j,:]@We[..])
__global__ __launch_bounds__(256, 3) void agg_kernel(
    const int* __restrict__ adj, const float* __restrict__ e,
    const float* __restrict__ ws, const float* __restrict__ x,
    float* __restrict__ hout)
{
    __shared__ __bf16 xls[64 * XLS_STRIDE];   // 33 KB: this WG's 64 h-rows
    __shared__ float red[4][64];
    const int bi   = blockIdx.x >> 1;         // b*256 + i
    const int hh   = blockIdx.x & 1;          // h half
    const int b    = bi >> 8;
    const int tid  = threadIdx.x;
    const int w    = tid >> 6;
    const int lane = tid & 63;
    const int quad = lane >> 4;
    const int col  = lane & 15;

    const size_t ebase   = (size_t)bi * (N_ * E_);
    const size_t adjbase = (size_t)bi * N_;

    // (1) Depth-2 e/adj prefetch issued FIRST (HBM/L3 latency elapses
    // during the staging below).
    float4 a0v[2], a1v[2];
    int4   avv[2];
#pragma unroll
    for (int p = 0; p < 2; ++p) {
        const int j0 = (p * 4 + w) * 16;
        const float* ap = e + ebase + (size_t)(j0 + col) * E_ + quad * 8;
        a0v[p] = *(const float4*)ap;
        a1v[p] = *(const float4*)(ap + 4);
        avv[p] = *(const int4*)(adj + adjbase + j0 + quad * 4);
    }

    // (2) Stage this half's xbT rows (64 x 256 bf16 = 32 KB) -> LDS.
    {
        const __bf16* gx = (const __bf16*)ws + (size_t)b * (H_ * N_)
                         + (size_t)(hh * 64) * N_;
#pragma unroll
        for (int it = 0; it < 8; ++it) {
            const int k   = it * 256 + tid;       // 16B-chunk index
            const int row = k >> 5, cc = k & 31;
            const f32x4 v = *(const f32x4*)(gx + (size_t)row * 256 + cc * 8);
            *(f32x4*)&xls[row * XLS_STRIDE + cc * 8] = v;
        }
    }

    // (3) We B-fragments for this half: 4 x dwordx4 (L2-hot table).
    const __bf16* Webf = (const __bf16*)(ws + WEBF_OFF);
    bf16x8 bw[4];
#pragma unroll
    for (int t = 0; t < 4; ++t)
        bw[t] = *(const bf16x8*)&Webf[(quad * 128 + hh * 64 + t * 16 + col) * 8];

    float psum[4];
#pragma unroll
    for (int t = 0; t < 4; ++t) psum[t] = 0.0f;

    const f32x4 zero4 = {0.0f, 0.0f, 0.0f, 0.0f};

    __syncthreads();   // xls staging complete

#pragma unroll
    for (int c = 0; c < 4; ++c) {
        const int s  = c & 1;
        const int jr = (c * 4 + w) * 16 + quad * 4;

        // Hoisted LDS xv reads for this chunk (4 x ds_read_b64, low pressure).
        bf16x4 xv[4];
#pragma unroll
        for (int t = 0; t < 4; ++t)
            xv[t] = *(const bf16x4*)&xls[(t * 16 + col) * XLS_STRIDE + jr];

        bf16x8 af;
        af[0] = f2bf(a0v[s].x); af[1] = f2bf(a0v[s].y);
        af[2] = f2bf(a0v[s].z); af[3] = f2bf(a0v[s].w);
        af[4] = f2bf(a1v[s].x); af[5] = f2bf(a1v[s].y);
        af[6] = f2bf(a1v[s].z); af[7] = f2bf(a1v[s].w);
        float adjf[4];
        adjf[0] = avv[s].x ? 1.0f : 0.0f;
        adjf[1] = avv[s].y ? 1.0f : 0.0f;
        adjf[2] = avv[s].z ? 1.0f : 0.0f;
        adjf[3] = avv[s].w ? 1.0f : 0.0f;

        // Refill this prefetch slot with chunk c+2.
        if (c < 2) {
            const int j0n = ((c + 2) * 4 + w) * 16;
            const float* apn = e + ebase + (size_t)(j0n + col) * E_ + quad * 8;
            a0v[s] = *(const float4*)apn;
            a1v[s] = *(const float4*)(apn + 4);
            avv[s] = *(const int4*)(adj + adjbase + j0n + quad * 4);
        }

        // 4 MFMAs (one group) + epilogue.
        f32x4 acc[4];
#pragma unroll
        for (int t = 0; t < 4; ++t)
            acc[t] = __builtin_amdgcn_mfma_f32_16x16x32_bf16(af, bw[t], zero4, 0, 0, 0);
#pragma unroll
        for (int t = 0; t < 4; ++t)
#pragma unroll
            for (int r = 0; r < 4; ++r)
                psum[t] += adjf[r] * fmaxf(acc[t][r] + (float)xv[t][r], 0.0f);
    }

    // Quad reduce in-register, wave reduce via LDS; h = agg + x residual.
#pragma unroll
    for (int t = 0; t < 4; ++t) {
        float v = psum[t];
        v += __shfl_xor(v, 16);
        v += __shfl_xor(v, 32);
        if (lane < 16) red[w][t * 16 + lane] = v;
    }
    __syncthreads();
    if (tid < 64) {
        const int hofs = hh * 64 + tid;
        const float aggv = red[0][tid] + red[1][tid] + red[2][tid] + red[3][tid];
        hout[(size_t)bi * H_ + hofs] = aggv + x[(size_t)bi * H_ + hofs];
    }
}

// MLP: out = relu(h@W1+b1)@W2 + b2, fp32, 8 rows/WG x 256 WGs.
// Weight L2 traffic: 256 WG x 262 KB = 67 MB. All weight loads f32x4 via
// transposed W1T/W2T. Reads h from d_out, overwrites the same 8 rows.
__global__ __launch_bounds__(256) void mlp_kernel(
    const float* __restrict__ ws, const float* __restrict__ b1,
    const float* __restrict__ b2, float* __restrict__ hio)
{
    __shared__ float hs[8][128];
    __shared__ float ts[8][256];
    __shared__ float part[8][2][128];
    const int tid = threadIdx.x;
    const int r0  = blockIdx.x * 8;

    ((f32x4*)hs)[tid] = ((const f32x4*)(hio + (size_t)r0 * H_))[tid];
    __syncthreads();

    // Layer 1: thread owns column tid for all 8 rows; W1T row = 128 floats.
    {
        const float* wrow = ws + W1T_OFF + (size_t)tid * 128;
        float acc[8] = {0.f, 0.f, 0.f, 0.f, 0.f, 0.f, 0.f, 0.f};
        for (int k = 0; k < 128; k += 4) {
            const f32x4 wv = *(const f32x4*)&wrow[k];
#pragma unroll
            for (int r = 0; r < 8; ++r) {
                const f32x4 hv = *(const f32x4*)&hs[r][k];   // LDS broadcast
                acc[r] += hv[0] * wv[0] + hv[1] * wv[1] + hv[2] * wv[2] + hv[3] * wv[3];
            }
        }
        const float bb = b1[tid];
#pragma unroll
        for (int r = 0; r < 8; ++r) ts[r][tid] = fmaxf(acc[r] + bb, 0.0f);
    }
    __syncthreads();

    // Layer 2: two threads per column (k split 128/128); W2T row = 256 floats.
    {
        const int c  = tid & 127;
        const int kb = (tid >> 7) * 128;
        const float* wrow = ws + W2T_OFF + (size_t)c * 256 + kb;
        float acc[8] = {0.f, 0.f, 0.f, 0.f, 0.f, 0.f, 0.f, 0.f};
        for (int k = 0; k < 128; k += 4) {
            const f32x4 wv = *(const f32x4*)&wrow[k];
#pragma unroll
            for (int r = 0; r < 8; ++r) {
                const f32x4 tv = *(const f32x4*)&ts[r][kb + k];  // 2-way bcast
                acc[r] += tv[0] * wv[0] + tv[1] * wv[1] + tv[2] * wv[2] + tv[3] * wv[3];
            }
        }
#pragma unroll
        for (int r = 0; r < 8; ++r) part[r][tid >> 7][c] = acc[r];
    }
    __syncthreads();
#pragma unroll
    for (int idx = tid; idx < 1024; idx += 256) {
        const int r = idx >> 7, c = idx & 127;
        hio[(size_t)(r0 + r) * H_ + c] = part[r][0][c] + part[r][1][c] + b2[c];
    }
}

extern "C" void kernel_launch(void* const* d_in, const int* in_sizes, int n_in,
                              void* d_out, int out_size, void* d_ws, size_t ws_size,
                              hipStream_t stream) {
    const float* x   = (const float*)d_in[0];
    const int*   adj = (const int*)  d_in[1];
    const float* e   = (const float*)d_in[2];
    const float* We  = (const float*)d_in[3];
    const float* be  = (const float*)d_in[4];
    const float* W1  = (const float*)d_in[5];
    const float* b1  = (const float*)d_in[6];
    const float* W2  = (const float*)d_in[7];
    const float* b2  = (const float*)d_in[8];
    float* out = (float*)d_out;
    float* ws  = (float*)d_ws;   // 776 KiB used (xbT bf16 + W1T + W2T + Webf)

    prep_kernel<<<dim3(321), dim3(256), 0, stream>>>(x, be, W1, W2, We, ws);
    agg_kernel<<<dim3(B_ * N_ * 2), dim3(256), 0, stream>>>(adj, e, ws, x, out);
    mlp_kernel<<<dim3(B_ * N_ / 8), dim3(256), 0, stream>>>(ws, b1, b2, out);
}